// Round 5
// baseline (6182.818 us; speedup 1.0000x reference)
//
#include <hip/hip_runtime.h>

typedef __bf16 bf16;
typedef __bf16 bf16x4 __attribute__((ext_vector_type(4)));
typedef __bf16 bf16x8 __attribute__((ext_vector_type(8)));
typedef float f32x4 __attribute__((ext_vector_type(4)));

#define MFMA_16x16x32(a, b, c) __builtin_amdgcn_mfma_f32_16x16x32_bf16((a), (b), (c), 0, 0, 0)

#define B_ 8
#define N_ 1024
#define C_ 768
#define H_ 12
#define HD_ 64
#define KDIM 768

__device__ __forceinline__ void gload_lds16(const void* g, void* l) {
  __builtin_amdgcn_global_load_lds(
      (const __attribute__((address_space(1))) void*)g,
      (__attribute__((address_space(3))) void*)l, 16, 0, 0);
}

// ---------------------------------------------------------------------------
// mask dtype detection (robust to int8/int32/int64 storage):
//   flags[0]=1 if any int32-view word > 1      -> byte-packed
//   flags[1]=1 if any ODD int32-view word != 0 -> int32 (int64 hi-words are 0)
// ---------------------------------------------------------------------------
__global__ __launch_bounds__(256) void detect_mask_kernel(const unsigned* __restrict__ m32,
                                                          int* __restrict__ flags) {
  const int i = blockIdx.x * 256 + threadIdx.x;
  if (i < 2048) {
    const unsigned v = m32[i];
    if (v > 1u) atomicOr(&flags[0], 1);
    if ((i & 1) && v != 0u) atomicOr(&flags[1], 1);
  }
}

// ---------------------------------------------------------------------------
// cvt: f32 -> bf16 for x, w_qkv, w_proj; bias[b*N+n] = mask ? -1e30 : log(size)
// ---------------------------------------------------------------------------
__global__ __launch_bounds__(256) void cvt_kernel(const float* __restrict__ x,
                                                  const float* __restrict__ wq,
                                                  const float* __restrict__ wp,
                                                  const float* __restrict__ size_in,
                                                  const void* __restrict__ mask_raw,
                                                  const int* __restrict__ flags,
                                                  bf16* __restrict__ xb,
                                                  bf16* __restrict__ wqb,
                                                  bf16* __restrict__ wpb,
                                                  float* __restrict__ biasb) {
  const int i = blockIdx.x * 256 + threadIdx.x;  // grid covers 6291456/4
  {
    const float4 v = ((const float4*)x)[i];
    bf16x4 o = {(bf16)v.x, (bf16)v.y, (bf16)v.z, (bf16)v.w};
    ((bf16x4*)xb)[i] = o;
  }
  if (i < 442368) {  // 2304*768/4
    const float4 v = ((const float4*)wq)[i];
    bf16x4 o = {(bf16)v.x, (bf16)v.y, (bf16)v.z, (bf16)v.w};
    ((bf16x4*)wqb)[i] = o;
  }
  if (i < 147456) {  // 768*768/4
    const float4 v = ((const float4*)wp)[i];
    bf16x4 o = {(bf16)v.x, (bf16)v.y, (bf16)v.z, (bf16)v.w};
    ((bf16x4*)wpb)[i] = o;
  }
  if (i < B_ * N_) {
    int mv;
    if (flags[0]) {
      mv = (int)((const unsigned char*)mask_raw)[i];
    } else if (flags[1]) {
      mv = ((const int*)mask_raw)[i];
    } else {  // int64
      const unsigned* m32 = (const unsigned*)mask_raw;
      mv = (int)(m32[2 * i] | m32[2 * i + 1]);
    }
    biasb[i] = mv ? -1e30f : logf(size_in[i]);
  }
}

// ---------------------------------------------------------------------------
// GEMM (NT): out[m][o] = sum_k A[m][k] * W[o][k].  M=8192, K=768.
// MODE 0: scatter epilogue into q/k/v, all [B,H,N,64] bf16
// MODE 1: f32 epilogue outf[m*768+o] = acc + bias[o]
// 128x128 tile, BK=64, 4 waves (2x2), each wave 64x64 = 4x4 frags of 16x16.
// ---------------------------------------------------------------------------
template <int MODE>
__global__ __launch_bounds__(256) void gemm_bt(const bf16* __restrict__ A,
                                               const bf16* __restrict__ W,
                                               const float* __restrict__ bias,
                                               bf16* __restrict__ out0,
                                               bf16* __restrict__ out1,
                                               bf16* __restrict__ out2,
                                               float* __restrict__ outf) {
  __shared__ bf16 As[128 * 64];
  __shared__ bf16 Bs[128 * 64];
  const int bid = blockIdx.x;
  const int mt = bid % 64;
  const int nt = bid / 64;
  const int t = threadIdx.x;
  const int lane = t & 63, w = t >> 6;
  const int wm = w >> 1, wn = w & 1;
  const int l15 = lane & 15, lg = lane >> 4;

  f32x4 acc[4][4] = {};

  const int srow = t >> 3;
  const int skel = (t & 7) * 8;
  const bf16* Ag = A + (size_t)(mt * 128) * KDIM;
  const bf16* Bg = W + (size_t)(nt * 128) * KDIM;

  for (int kt = 0; kt < KDIM; kt += 64) {
#pragma unroll
    for (int c = 0; c < 4; ++c) {
      gload_lds16(Ag + (size_t)(c * 32 + srow) * KDIM + kt + skel,
                  (char*)As + c * 4096 + w * 1024);
      gload_lds16(Bg + (size_t)(c * 32 + srow) * KDIM + kt + skel,
                  (char*)Bs + c * 4096 + w * 1024);
    }
    __syncthreads();
#pragma unroll
    for (int ks = 0; ks < 2; ++ks) {
      bf16x8 af[4], bfr[4];
#pragma unroll
      for (int i = 0; i < 4; ++i)
        af[i] = *(const bf16x8*)(As + (wm * 64 + i * 16 + l15) * 64 + ks * 32 + lg * 8);
#pragma unroll
      for (int i = 0; i < 4; ++i)
        bfr[i] = *(const bf16x8*)(Bs + (wn * 64 + i * 16 + l15) * 64 + ks * 32 + lg * 8);
#pragma unroll
      for (int i = 0; i < 4; ++i)
#pragma unroll
        for (int j = 0; j < 4; ++j)
          acc[i][j] = MFMA_16x16x32(af[i], bfr[j], acc[i][j]);
    }
    __syncthreads();
  }

  if (MODE == 0) {
    const int which = (nt * 128) / 768;  // 768 = 6*128, tiles never straddle
#pragma unroll
    for (int i = 0; i < 4; ++i)
#pragma unroll
      for (int j = 0; j < 4; ++j)
#pragma unroll
        for (int r = 0; r < 4; ++r) {
          const int m = mt * 128 + wm * 64 + i * 16 + lg * 4 + r;
          const int o = nt * 128 + wn * 64 + j * 16 + l15;
          const int b = m >> 10, n = m & 1023;
          const int f = o - which * 768;
          const int h = f >> 6, hd = f & 63;
          const bf16 bv = (bf16)acc[i][j][r];
          const size_t idx = (((size_t)(b * 12 + h)) * 1024 + n) * 64 + hd;
          if (which == 0)
            out0[idx] = bv;
          else if (which == 1)
            out1[idx] = bv;
          else
            out2[idx] = bv;
        }
  } else {
#pragma unroll
    for (int i = 0; i < 4; ++i)
#pragma unroll
      for (int j = 0; j < 4; ++j) {
        const int o = nt * 128 + wn * 64 + j * 16 + l15;
        const float bv = bias[o];
#pragma unroll
        for (int r = 0; r < 4; ++r) {
          const int m = mt * 128 + wm * 64 + i * 16 + lg * 4 + r;
          outf[(size_t)m * 768 + o] = acc[i][j][r] + bv;
        }
      }
  }
}

// ---------------------------------------------------------------------------
// k_mean (f32 out): kmean[b,n,hd] = mean_h k[b,h,n,hd]
// ---------------------------------------------------------------------------
__global__ __launch_bounds__(256) void kmean_kernel(const bf16* __restrict__ kbuf,
                                                    float* __restrict__ kmean) {
  const int i = blockIdx.x * 256 + threadIdx.x;
  if (i >= B_ * N_ * HD_) return;
  const int hd = i & 63;
  const int n = (i >> 6) & 1023;
  const int b = i >> 16;
  float s = 0.f;
#pragma unroll
  for (int h = 0; h < 12; ++h)
    s += (float)kbuf[(((size_t)(b * 12 + h)) * 1024 + n) * 64 + hd];
  kmean[i] = s * (1.0f / 12.0f);
}

// ---------------------------------------------------------------------------
// Simple attention: 1 wave per q-row, lane = head-dim. f32 online softmax.
// ---------------------------------------------------------------------------
__global__ __launch_bounds__(256) void attn_simple(const bf16* __restrict__ qbuf,
                                                   const bf16* __restrict__ kbuf,
                                                   const bf16* __restrict__ vbuf,
                                                   const float* __restrict__ biasb,
                                                   bf16* __restrict__ outws) {
  const int t = threadIdx.x, lane = t & 63, wv = t >> 6;
  const int gw = blockIdx.x * 4 + wv;  // (b,h,n) row
  const int n = gw & 1023;
  const int bh = gw >> 10;
  const int b = bh / 12, h = bh % 12;
  const bf16* Kp = kbuf + (size_t)bh * 65536;
  const bf16* Vp = vbuf + (size_t)bh * 65536;
  const float* bias = biasb + b * 1024;
  const float qv = (float)qbuf[(size_t)bh * 65536 + n * 64 + lane];

  float m = -1e30f, l = 0.f, acc = 0.f;
  for (int key = 0; key < 1024; ++key) {
    float s = qv * (float)Kp[key * 64 + lane];
#pragma unroll
    for (int off = 1; off < 64; off <<= 1) s += __shfl_xor(s, off, 64);
    s = s * 0.125f + bias[key];
    const float nm = fmaxf(m, s);
    const float f = __expf(m - nm);
    const float p = __expf(s - nm);
    const float vvv = (float)Vp[key * 64 + lane];
    l = l * f + p;
    acc = acc * f + p * vvv;
    m = nm;
  }
  outws[((size_t)b * 1024 + n) * 768 + h * 64 + lane] = (bf16)(acc / l);
}

// ---------------------------------------------------------------------------
extern "C" void kernel_launch(void* const* d_in, const int* in_sizes, int n_in,
                              void* d_out, int out_size, void* d_ws, size_t ws_size,
                              hipStream_t stream) {
  const float* x       = (const float*)d_in[0];
  const float* size_in = (const float*)d_in[1];
  const void*  mask    = d_in[2];
  const float* w_qkv   = (const float*)d_in[3];
  const float* w_proj  = (const float*)d_in[4];
  const float* b_proj  = (const float*)d_in[5];
  float* out = (float*)d_out;   // f32 outputs per reference dtype

  if (n_in < 6 ||
      in_sizes[0] != 6291456 || in_sizes[1] != 8192 || in_sizes[2] != 8192 ||
      in_sizes[3] != 1769472 || in_sizes[4] != 589824 || in_sizes[5] != 768)
    return;

  const size_t QS = (size_t)B_ * H_ * N_ * HD_;  // 6291456 elems
  // bytes: 4*12582912 (xb,q,k,v bf16) + 3538944 (wqb) + 1179648 (wpb)
  //        + 32768 (biasb) + 16 (flags) = 55083024
  if (ws_size < 55083024) return;  // signature: absmax == 0.5508

  bf16* xb    = (bf16*)d_ws;       // dead after gemm<0>; reused as attnw
  bf16* qbuf  = xb + QS;
  bf16* kbuf  = qbuf + QS;
  bf16* vbuf  = kbuf + QS;
  bf16* wqb   = vbuf + QS;         // 1769472 elems
  bf16* wpb   = wqb + 1769472;     // 589824 elems
  float* biasb = (float*)(wpb + 589824);
  int* flags = (int*)(biasb + 8192);
  bf16* attnw = xb;

  hipMemsetAsync(flags, 0, 8, stream);
  detect_mask_kernel<<<8, 256, 0, stream>>>((const unsigned*)mask, flags);
  cvt_kernel<<<6144, 256, 0, stream>>>(x, w_qkv, w_proj, size_in, mask, flags,
                                       xb, wqb, wpb, biasb);
  gemm_bt<0><<<64 * 18, 256, 0, stream>>>(xb, wqb, nullptr, qbuf, kbuf, vbuf, nullptr);
  kmean_kernel<<<2048, 256, 0, stream>>>(kbuf, out + (size_t)B_ * N_ * C_);
  attn_simple<<<24576, 256, 0, stream>>>(qbuf, kbuf, vbuf, biasb, attnw);
  gemm_bt<1><<<64 * 6, 256, 0, stream>>>(attnw, wpb, b_proj, nullptr, nullptr, nullptr, out);
}

// Round 6
// 317.308 us; speedup vs baseline: 19.4852x; 19.4852x over previous
//
#include <hip/hip_runtime.h>

typedef __bf16 bf16;
typedef __bf16 bf16x4 __attribute__((ext_vector_type(4)));
typedef __bf16 bf16x8 __attribute__((ext_vector_type(8)));
typedef float f32x4 __attribute__((ext_vector_type(4)));

#define MFMA_16x16x32(a, b, c) __builtin_amdgcn_mfma_f32_16x16x32_bf16((a), (b), (c), 0, 0, 0)

#define B_ 8
#define N_ 1024
#define C_ 768
#define H_ 12
#define HD_ 64
#define KDIM 768

__device__ __forceinline__ void gload_lds16(const void* g, void* l) {
  __builtin_amdgcn_global_load_lds(
      (const __attribute__((address_space(1))) void*)g,
      (__attribute__((address_space(3))) void*)l, 16, 0, 0);
}

// ---------------------------------------------------------------------------
// mask dtype detection (robust to int8/int32/int64 storage)
// ---------------------------------------------------------------------------
__global__ __launch_bounds__(256) void detect_mask_kernel(const unsigned* __restrict__ m32,
                                                          int* __restrict__ flags) {
  const int i = blockIdx.x * 256 + threadIdx.x;
  if (i < 2048) {
    const unsigned v = m32[i];
    if (v > 1u) atomicOr(&flags[0], 1);
    if ((i & 1) && v != 0u) atomicOr(&flags[1], 1);
  }
}

// ---------------------------------------------------------------------------
// cvt: f32 -> bf16 for x, w_qkv, w_proj; bias[b*N+n] = mask ? -1e30 : log(size)
// ---------------------------------------------------------------------------
__global__ __launch_bounds__(256) void cvt_kernel(const float* __restrict__ x,
                                                  const float* __restrict__ wq,
                                                  const float* __restrict__ wp,
                                                  const float* __restrict__ size_in,
                                                  const void* __restrict__ mask_raw,
                                                  const int* __restrict__ flags,
                                                  bf16* __restrict__ xb,
                                                  bf16* __restrict__ wqb,
                                                  bf16* __restrict__ wpb,
                                                  float* __restrict__ biasb) {
  const int i = blockIdx.x * 256 + threadIdx.x;  // grid covers 6291456/4
  {
    const float4 v = ((const float4*)x)[i];
    bf16x4 o = {(bf16)v.x, (bf16)v.y, (bf16)v.z, (bf16)v.w};
    ((bf16x4*)xb)[i] = o;
  }
  if (i < 442368) {  // 2304*768/4
    const float4 v = ((const float4*)wq)[i];
    bf16x4 o = {(bf16)v.x, (bf16)v.y, (bf16)v.z, (bf16)v.w};
    ((bf16x4*)wqb)[i] = o;
  }
  if (i < 147456) {  // 768*768/4
    const float4 v = ((const float4*)wp)[i];
    bf16x4 o = {(bf16)v.x, (bf16)v.y, (bf16)v.z, (bf16)v.w};
    ((bf16x4*)wpb)[i] = o;
  }
  if (i < B_ * N_) {
    int mv;
    if (flags[0]) {
      mv = (int)((const unsigned char*)mask_raw)[i];
    } else if (flags[1]) {
      mv = ((const int*)mask_raw)[i];
    } else {  // int64
      const unsigned* m32 = (const unsigned*)mask_raw;
      mv = (int)(m32[2 * i] | m32[2 * i + 1]);
    }
    biasb[i] = mv ? -1e30f : logf(size_in[i]);
  }
}

// ---------------------------------------------------------------------------
// GEMM (NT): out[m][o] = sum_k A[m][k] * W[o][k].  M=8192, K=768.
// MODE 0: scatter epilogue into q[B,H,N,64], k[B,H,N,64], vt[B,H,64,N]
// MODE 1: f32 epilogue outf[m*768+o] = acc + bias[o]
// ---------------------------------------------------------------------------
template <int MODE>
__global__ __launch_bounds__(256) void gemm_bt(const bf16* __restrict__ A,
                                               const bf16* __restrict__ W,
                                               const float* __restrict__ bias,
                                               bf16* __restrict__ out0,
                                               bf16* __restrict__ out1,
                                               bf16* __restrict__ out2,
                                               float* __restrict__ outf) {
  __shared__ bf16 As[128 * 64];
  __shared__ bf16 Bs[128 * 64];
  const int bid = blockIdx.x;
  const int mt = bid % 64;
  const int nt = bid / 64;
  const int t = threadIdx.x;
  const int lane = t & 63, w = t >> 6;
  const int wm = w >> 1, wn = w & 1;
  const int l15 = lane & 15, lg = lane >> 4;

  f32x4 acc[4][4] = {};

  const int srow = t >> 3;
  const int skel = (t & 7) * 8;
  const bf16* Ag = A + (size_t)(mt * 128) * KDIM;
  const bf16* Bg = W + (size_t)(nt * 128) * KDIM;

  for (int kt = 0; kt < KDIM; kt += 64) {
#pragma unroll
    for (int c = 0; c < 4; ++c) {
      gload_lds16(Ag + (size_t)(c * 32 + srow) * KDIM + kt + skel,
                  (char*)As + c * 4096 + w * 1024);
      gload_lds16(Bg + (size_t)(c * 32 + srow) * KDIM + kt + skel,
                  (char*)Bs + c * 4096 + w * 1024);
    }
    __syncthreads();
#pragma unroll
    for (int ks = 0; ks < 2; ++ks) {
      bf16x8 af[4], bfr[4];
#pragma unroll
      for (int i = 0; i < 4; ++i)
        af[i] = *(const bf16x8*)(As + (wm * 64 + i * 16 + l15) * 64 + ks * 32 + lg * 8);
#pragma unroll
      for (int i = 0; i < 4; ++i)
        bfr[i] = *(const bf16x8*)(Bs + (wn * 64 + i * 16 + l15) * 64 + ks * 32 + lg * 8);
#pragma unroll
      for (int i = 0; i < 4; ++i)
#pragma unroll
        for (int j = 0; j < 4; ++j)
          acc[i][j] = MFMA_16x16x32(af[i], bfr[j], acc[i][j]);
    }
    __syncthreads();
  }

  if (MODE == 0) {
    const int which = (nt * 128) / 768;  // 768 = 6*128, tiles never straddle
#pragma unroll
    for (int i = 0; i < 4; ++i)
#pragma unroll
      for (int j = 0; j < 4; ++j)
#pragma unroll
        for (int r = 0; r < 4; ++r) {
          const int m = mt * 128 + wm * 64 + i * 16 + lg * 4 + r;
          const int o = nt * 128 + wn * 64 + j * 16 + l15;
          const int b = m >> 10, n = m & 1023;
          const int f = o - which * 768;
          const int h = f >> 6, hd = f & 63;
          const bf16 bv = (bf16)acc[i][j][r];
          if (which == 0)
            out0[(((size_t)(b * 12 + h)) * 1024 + n) * 64 + hd] = bv;
          else if (which == 1)
            out1[(((size_t)(b * 12 + h)) * 1024 + n) * 64 + hd] = bv;
          else
            out2[(((size_t)(b * 12 + h)) * 64 + hd) * 1024 + n] = bv;
        }
  } else {
#pragma unroll
    for (int i = 0; i < 4; ++i)
#pragma unroll
      for (int j = 0; j < 4; ++j) {
        const int o = nt * 128 + wn * 64 + j * 16 + l15;
        const float bv = bias[o];
#pragma unroll
        for (int r = 0; r < 4; ++r) {
          const int m = mt * 128 + wm * 64 + i * 16 + lg * 4 + r;
          outf[(size_t)m * 768 + o] = acc[i][j][r] + bv;
        }
      }
  }
}

// ---------------------------------------------------------------------------
// k_mean (f32 out): kmean[b,n,hd] = mean_h k[b,h,n,hd]
// ---------------------------------------------------------------------------
__global__ __launch_bounds__(256) void kmean_kernel(const bf16* __restrict__ kbuf,
                                                    float* __restrict__ kmean) {
  const int i = blockIdx.x * 256 + threadIdx.x;
  if (i >= B_ * N_ * HD_) return;
  const int hd = i & 63;
  const int n = (i >> 6) & 1023;
  const int b = i >> 16;
  float s = 0.f;
#pragma unroll
  for (int h = 0; h < 12; ++h)
    s += (float)kbuf[(((size_t)(b * 12 + h)) * 1024 + n) * 64 + hd];
  kmean[i] = s * (1.0f / 12.0f);
}

// ---------------------------------------------------------------------------
// MFMA flash attention. Block = 4 waves, each wave: 16 q-rows, KBLK=32.
// No K/V LDS staging (256KB/head-batch, L2-resident). P goes D-layout ->
// per-wave LDS -> A-layout. V consumed from transposed vt[B,H,64,N].
// Frag conventions (validated by gemm_bt pass): A row=l15,k=lg*8;
// B col=l15,k=lg*8; D row=lg*4+reg,col=l15.
// ---------------------------------------------------------------------------
__global__ __launch_bounds__(256) void attn_mfma(const bf16* __restrict__ qbuf,
                                                 const bf16* __restrict__ kbuf,
                                                 const bf16* __restrict__ vtbuf,
                                                 const float* __restrict__ biasb,
                                                 bf16* __restrict__ outws) {
  __shared__ bf16 plds[4][16][32];
  const int qt = blockIdx.x & 15;
  const int bh = blockIdx.x >> 4;
  const int b = bh / 12, h = bh % 12;
  const int t = threadIdx.x, lane = t & 63, w = t >> 6;
  const int l15 = lane & 15, lg = lane >> 4;
  const int qbase = qt * 64 + w * 16;

  const bf16* Q = qbuf + ((size_t)bh * 1024 + qbase) * 64;
  const bf16* Kp = kbuf + (size_t)bh * 65536;
  const bf16* Vt = vtbuf + (size_t)bh * 65536;
  const float* bias = biasb + b * 1024;

  bf16x8 qa0 = *(const bf16x8*)(Q + l15 * 64 + lg * 8);
  bf16x8 qa1 = *(const bf16x8*)(Q + l15 * 64 + 32 + lg * 8);

  f32x4 oacc[4] = {};
  float mrow[4], lrow[4];
#pragma unroll
  for (int j = 0; j < 4; ++j) { mrow[j] = -1e30f; lrow[j] = 0.f; }

  for (int kb = 0; kb < 1024; kb += 32) {
    float sv[2][4];
#pragma unroll
    for (int kf = 0; kf < 2; ++kf) {
      const bf16* Krow = Kp + (size_t)(kb + kf * 16 + l15) * 64;
      bf16x8 kf0 = *(const bf16x8*)(Krow + lg * 8);
      bf16x8 kf1 = *(const bf16x8*)(Krow + 32 + lg * 8);
      f32x4 z = {};
      z = MFMA_16x16x32(qa0, kf0, z);
      z = MFMA_16x16x32(qa1, kf1, z);
      const float bia = bias[kb + kf * 16 + l15];
#pragma unroll
      for (int j = 0; j < 4; ++j) sv[kf][j] = z[j] * 0.125f + bia;
    }
    // row max over 32 keys: pairwise over frags, then 16-lane (l15) reduce
    float mx[4];
#pragma unroll
    for (int j = 0; j < 4; ++j) mx[j] = fmaxf(sv[0][j], sv[1][j]);
#pragma unroll
    for (int off = 1; off < 16; off <<= 1)
#pragma unroll
      for (int j = 0; j < 4; ++j) mx[j] = fmaxf(mx[j], __shfl_xor(mx[j], off, 64));

    float resc[4];
#pragma unroll
    for (int j = 0; j < 4; ++j) {
      const float mn = fmaxf(mrow[j], mx[j]);
      resc[j] = __expf(mrow[j] - mn);
      mrow[j] = mn;
    }
    float ps[2][4], rs[4] = {0.f, 0.f, 0.f, 0.f};
#pragma unroll
    for (int kf = 0; kf < 2; ++kf)
#pragma unroll
      for (int j = 0; j < 4; ++j) {
        const float p = __expf(sv[kf][j] - mrow[j]);
        ps[kf][j] = p;
        rs[j] += p;
      }
#pragma unroll
    for (int off = 1; off < 16; off <<= 1)
#pragma unroll
      for (int j = 0; j < 4; ++j) rs[j] += __shfl_xor(rs[j], off, 64);
#pragma unroll
    for (int j = 0; j < 4; ++j) lrow[j] = lrow[j] * resc[j] + rs[j];
#pragma unroll
    for (int df = 0; df < 4; ++df) {
      f32x4 t4 = oacc[df];
#pragma unroll
      for (int j = 0; j < 4; ++j) t4[j] *= resc[j];
      oacc[df] = t4;
    }
    // P: D-layout -> LDS [q][key] -> A-layout (per-wave slice, in-wave RAW)
#pragma unroll
    for (int kf = 0; kf < 2; ++kf)
#pragma unroll
      for (int j = 0; j < 4; ++j)
        plds[w][lg * 4 + j][kf * 16 + l15] = (bf16)ps[kf][j];

    bf16x8 pa = *(const bf16x8*)(&plds[w][l15][lg * 8]);
#pragma unroll
    for (int df = 0; df < 4; ++df) {
      const bf16* Vr = Vt + (size_t)(df * 16 + l15) * 1024 + kb + lg * 8;
      bf16x8 vb = *(const bf16x8*)Vr;
      oacc[df] = MFMA_16x16x32(pa, vb, oacc[df]);
    }
  }

#pragma unroll
  for (int df = 0; df < 4; ++df)
#pragma unroll
    for (int j = 0; j < 4; ++j) {
      const int n = qbase + lg * 4 + j;
      const int c = h * 64 + df * 16 + l15;
      outws[((size_t)b * 1024 + n) * 768 + c] = (bf16)(oacc[df][j] / lrow[j]);
    }
}

// ---------------------------------------------------------------------------
extern "C" void kernel_launch(void* const* d_in, const int* in_sizes, int n_in,
                              void* d_out, int out_size, void* d_ws, size_t ws_size,
                              hipStream_t stream) {
  const float* x       = (const float*)d_in[0];
  const float* size_in = (const float*)d_in[1];
  const void*  mask    = d_in[2];
  const float* w_qkv   = (const float*)d_in[3];
  const float* w_proj  = (const float*)d_in[4];
  const float* b_proj  = (const float*)d_in[5];
  float* out = (float*)d_out;   // f32 outputs per reference dtype

  if (n_in < 6 ||
      in_sizes[0] != 6291456 || in_sizes[1] != 8192 || in_sizes[2] != 8192 ||
      in_sizes[3] != 1769472 || in_sizes[4] != 589824 || in_sizes[5] != 768)
    return;

  const size_t QS = (size_t)B_ * H_ * N_ * HD_;  // 6291456 elems
  if (ws_size < 55083024) return;

  bf16* xb    = (bf16*)d_ws;       // dead after gemm<0>; reused as attnw
  bf16* qbuf  = xb + QS;
  bf16* kbuf  = qbuf + QS;
  bf16* vtbuf = kbuf + QS;
  bf16* wqb   = vtbuf + QS;        // 1769472 elems
  bf16* wpb   = wqb + 1769472;     // 589824 elems
  float* biasb = (float*)(wpb + 589824);
  int* flags = (int*)(biasb + 8192);
  bf16* attnw = xb;

  hipMemsetAsync(flags, 0, 8, stream);
  detect_mask_kernel<<<8, 256, 0, stream>>>((const unsigned*)mask, flags);
  cvt_kernel<<<6144, 256, 0, stream>>>(x, w_qkv, w_proj, size_in, mask, flags,
                                       xb, wqb, wpb, biasb);
  gemm_bt<0><<<64 * 18, 256, 0, stream>>>(xb, wqb, nullptr, qbuf, kbuf, vtbuf, nullptr);
  kmean_kernel<<<2048, 256, 0, stream>>>(kbuf, out + (size_t)B_ * N_ * C_);
  attn_mfma<<<1536, 256, 0, stream>>>(qbuf, kbuf, vtbuf, biasb, attnw);
  gemm_bt<1><<<64 * 6, 256, 0, stream>>>(attnw, wpb, b_proj, nullptr, nullptr, nullptr, out);
}

// Round 7
// 302.854 us; speedup vs baseline: 20.4152x; 1.0477x over previous
//
#include <hip/hip_runtime.h>

typedef __bf16 bf16;
typedef __bf16 bf16x4 __attribute__((ext_vector_type(4)));
typedef __bf16 bf16x8 __attribute__((ext_vector_type(8)));
typedef float f32x4 __attribute__((ext_vector_type(4)));

#define MFMA_16x16x32(a, b, c) __builtin_amdgcn_mfma_f32_16x16x32_bf16((a), (b), (c), 0, 0, 0)

#define B_ 8
#define N_ 1024
#define C_ 768
#define H_ 12
#define HD_ 64
#define KDIM 768

__device__ __forceinline__ void gload_lds16(const void* g, void* l) {
  __builtin_amdgcn_global_load_lds(
      (const __attribute__((address_space(1))) void*)g,
      (__attribute__((address_space(3))) void*)l, 16, 0, 0);
}

// ---------------------------------------------------------------------------
// mask dtype detection (robust to int8/int32/int64 storage)
// ---------------------------------------------------------------------------
__global__ __launch_bounds__(256) void detect_mask_kernel(const unsigned* __restrict__ m32,
                                                          int* __restrict__ flags) {
  const int i = blockIdx.x * 256 + threadIdx.x;
  if (i < 2048) {
    const unsigned v = m32[i];
    if (v > 1u) atomicOr(&flags[0], 1);
    if ((i & 1) && v != 0u) atomicOr(&flags[1], 1);
  }
}

// ---------------------------------------------------------------------------
// cvt: f32 -> bf16 for x, w_qkv, w_proj; bias[b*N+n] = mask ? -1e30 : log(size)
// ---------------------------------------------------------------------------
__global__ __launch_bounds__(256) void cvt_kernel(const float* __restrict__ x,
                                                  const float* __restrict__ wq,
                                                  const float* __restrict__ wp,
                                                  const float* __restrict__ size_in,
                                                  const void* __restrict__ mask_raw,
                                                  const int* __restrict__ flags,
                                                  bf16* __restrict__ xb,
                                                  bf16* __restrict__ wqb,
                                                  bf16* __restrict__ wpb,
                                                  float* __restrict__ biasb) {
  const int i = blockIdx.x * 256 + threadIdx.x;  // grid covers 6291456/4
  {
    const float4 v = ((const float4*)x)[i];
    bf16x4 o = {(bf16)v.x, (bf16)v.y, (bf16)v.z, (bf16)v.w};
    ((bf16x4*)xb)[i] = o;
  }
  if (i < 442368) {  // 2304*768/4
    const float4 v = ((const float4*)wq)[i];
    bf16x4 o = {(bf16)v.x, (bf16)v.y, (bf16)v.z, (bf16)v.w};
    ((bf16x4*)wqb)[i] = o;
  }
  if (i < 147456) {  // 768*768/4
    const float4 v = ((const float4*)wp)[i];
    bf16x4 o = {(bf16)v.x, (bf16)v.y, (bf16)v.z, (bf16)v.w};
    ((bf16x4*)wpb)[i] = o;
  }
  if (i < B_ * N_) {
    int mv;
    if (flags[0]) {
      mv = (int)((const unsigned char*)mask_raw)[i];
    } else if (flags[1]) {
      mv = ((const int*)mask_raw)[i];
    } else {  // int64
      const unsigned* m32 = (const unsigned*)mask_raw;
      mv = (int)(m32[2 * i] | m32[2 * i + 1]);
    }
    biasb[i] = mv ? -1e30f : logf(size_in[i]);
  }
}

// ---------------------------------------------------------------------------
// GEMM (NT): out[m][o] = sum_k A[m][k] * W[o][k].  M=8192, K=768.
// MODE 0: scatter epilogue into q[B,H,N,64], k[B,H,N,64], vt[B,H,64,N]
// MODE 1: f32 epilogue outf[m*768+o] = acc + bias[o]
// ---------------------------------------------------------------------------
template <int MODE>
__global__ __launch_bounds__(256) void gemm_bt(const bf16* __restrict__ A,
                                               const bf16* __restrict__ W,
                                               const float* __restrict__ bias,
                                               bf16* __restrict__ out0,
                                               bf16* __restrict__ out1,
                                               bf16* __restrict__ out2,
                                               float* __restrict__ outf) {
  __shared__ bf16 As[128 * 64];
  __shared__ bf16 Bs[128 * 64];
  const int bid = blockIdx.x;
  const int mt = bid % 64;
  const int nt = bid / 64;
  const int t = threadIdx.x;
  const int lane = t & 63, w = t >> 6;
  const int wm = w >> 1, wn = w & 1;
  const int l15 = lane & 15, lg = lane >> 4;

  f32x4 acc[4][4] = {};

  const int srow = t >> 3;
  const int skel = (t & 7) * 8;
  const bf16* Ag = A + (size_t)(mt * 128) * KDIM;
  const bf16* Bg = W + (size_t)(nt * 128) * KDIM;

  for (int kt = 0; kt < KDIM; kt += 64) {
#pragma unroll
    for (int c = 0; c < 4; ++c) {
      gload_lds16(Ag + (size_t)(c * 32 + srow) * KDIM + kt + skel,
                  (char*)As + c * 4096 + w * 1024);
      gload_lds16(Bg + (size_t)(c * 32 + srow) * KDIM + kt + skel,
                  (char*)Bs + c * 4096 + w * 1024);
    }
    __syncthreads();
#pragma unroll
    for (int ks = 0; ks < 2; ++ks) {
      bf16x8 af[4], bfr[4];
#pragma unroll
      for (int i = 0; i < 4; ++i)
        af[i] = *(const bf16x8*)(As + (wm * 64 + i * 16 + l15) * 64 + ks * 32 + lg * 8);
#pragma unroll
      for (int i = 0; i < 4; ++i)
        bfr[i] = *(const bf16x8*)(Bs + (wn * 64 + i * 16 + l15) * 64 + ks * 32 + lg * 8);
#pragma unroll
      for (int i = 0; i < 4; ++i)
#pragma unroll
        for (int j = 0; j < 4; ++j)
          acc[i][j] = MFMA_16x16x32(af[i], bfr[j], acc[i][j]);
    }
    __syncthreads();
  }

  if (MODE == 0) {
    const int which = (nt * 128) / 768;  // 768 = 6*128, tiles never straddle
#pragma unroll
    for (int i = 0; i < 4; ++i)
#pragma unroll
      for (int j = 0; j < 4; ++j)
#pragma unroll
        for (int r = 0; r < 4; ++r) {
          const int m = mt * 128 + wm * 64 + i * 16 + lg * 4 + r;
          const int o = nt * 128 + wn * 64 + j * 16 + l15;
          const int b = m >> 10, n = m & 1023;
          const int f = o - which * 768;
          const int h = f >> 6, hd = f & 63;
          const bf16 bv = (bf16)acc[i][j][r];
          if (which == 0)
            out0[(((size_t)(b * 12 + h)) * 1024 + n) * 64 + hd] = bv;
          else if (which == 1)
            out1[(((size_t)(b * 12 + h)) * 1024 + n) * 64 + hd] = bv;
          else
            out2[(((size_t)(b * 12 + h)) * 64 + hd) * 1024 + n] = bv;
        }
  } else {
#pragma unroll
    for (int i = 0; i < 4; ++i)
#pragma unroll
      for (int j = 0; j < 4; ++j) {
        const int o = nt * 128 + wn * 64 + j * 16 + l15;
        const float bv = bias[o];
#pragma unroll
        for (int r = 0; r < 4; ++r) {
          const int m = mt * 128 + wm * 64 + i * 16 + lg * 4 + r;
          outf[(size_t)m * 768 + o] = acc[i][j][r] + bv;
        }
      }
  }
}

// ---------------------------------------------------------------------------
// k_mean (f32 out): kmean[b,n,hd] = mean_h k[b,h,n,hd]
// ---------------------------------------------------------------------------
__global__ __launch_bounds__(256) void kmean_kernel(const bf16* __restrict__ kbuf,
                                                    float* __restrict__ kmean) {
  const int i = blockIdx.x * 256 + threadIdx.x;
  if (i >= B_ * N_ * HD_) return;
  const int hd = i & 63;
  const int n = (i >> 6) & 1023;
  const int b = i >> 16;
  float s = 0.f;
#pragma unroll
  for (int h = 0; h < 12; ++h)
    s += (float)kbuf[(((size_t)(b * 12 + h)) * 1024 + n) * 64 + hd];
  kmean[i] = s * (1.0f / 12.0f);
}

// ---------------------------------------------------------------------------
// MFMA flash attention, swapped-operand form. Block = 4 waves, wave = 16
// q-rows, KBLK = 64. S^T = mfma(A=K, B=Q): D col=l15=q, row=key -> softmax
// is lane-local + 2 shuffles (xor 16/32). K-rows are loaded PERMUTED per
// frag: pi_f(m) = 32*(f>>1) + 8*(m>>2) + 4*(f&1) + (m&3), so each lane's
// P values land in natural PV B-frag slot order: P never leaves the lane
// (no LDS, no bank conflicts). Bias indexed through the same permutation.
// V consumed from transposed vt[B,H,64,N] as contiguous 16B A-frags.
// ---------------------------------------------------------------------------
__global__ __launch_bounds__(256) void attn_mfma(const bf16* __restrict__ qbuf,
                                                 const bf16* __restrict__ kbuf,
                                                 const bf16* __restrict__ vtbuf,
                                                 const float* __restrict__ biasb,
                                                 bf16* __restrict__ outws) {
  const int qt = blockIdx.x & 15;
  const int bh = blockIdx.x >> 4;
  const int b = bh / 12, h = bh % 12;
  const int t = threadIdx.x, lane = t & 63, w = t >> 6;
  const int l15 = lane & 15, lg = lane >> 4;
  const int qbase = qt * 64 + w * 16;

  const bf16* Q = qbuf + ((size_t)bh * 1024 + qbase) * 64;
  const bf16* Kp = kbuf + (size_t)bh * 65536;
  const bf16* Vt = vtbuf + (size_t)bh * 65536;
  const float* bias = biasb + b * 1024;

  // Q as B-operand: col=l15 (q-row), k-slots lg*8+e = d (natural order)
  const bf16x8 qb0 = *(const bf16x8*)(Q + l15 * 64 + lg * 8);
  const bf16x8 qb1 = *(const bf16x8*)(Q + l15 * 64 + 32 + lg * 8);

  const int r0 = 8 * (l15 >> 2) + (l15 & 3);  // permuted K-row base (A-row=l15)
  const int bb0 = 8 * lg;                     // bias quad base (D-row=lg*4+j)

  f32x4 oacc[4] = {};
  float m = -1e30f, l = 0.f;

  for (int kb = 0; kb < 1024; kb += 64) {
    float sv[4][4];
#pragma unroll
    for (int f = 0; f < 4; ++f) {
      const int cf = 32 * (f >> 1) + 4 * (f & 1);
      const bf16* Krow = Kp + (size_t)(kb + cf + r0) * 64;
      const bf16x8 ka0 = *(const bf16x8*)(Krow + lg * 8);
      const bf16x8 ka1 = *(const bf16x8*)(Krow + 32 + lg * 8);
      f32x4 z = {};
      z = MFMA_16x16x32(ka0, qb0, z);
      z = MFMA_16x16x32(ka1, qb1, z);
      const float4 bi = *(const float4*)(bias + kb + cf + bb0);
      sv[f][0] = z[0] * 0.125f + bi.x;
      sv[f][1] = z[1] * 0.125f + bi.y;
      sv[f][2] = z[2] * 0.125f + bi.z;
      sv[f][3] = z[3] * 0.125f + bi.w;
    }
    // max over 64 keys for this lane's q=l15: 15 local + 2 shuffles
    float mx = sv[0][0];
#pragma unroll
    for (int f = 0; f < 4; ++f)
#pragma unroll
      for (int j = 0; j < 4; ++j) mx = fmaxf(mx, sv[f][j]);
    mx = fmaxf(mx, __shfl_xor(mx, 16, 64));
    mx = fmaxf(mx, __shfl_xor(mx, 32, 64));
    const float mn = fmaxf(m, mx);
    const float resc = __expf(m - mn);
    m = mn;

    float rs = 0.f;
    bf16x8 pa0, pa1;
#pragma unroll
    for (int f = 0; f < 4; ++f)
#pragma unroll
      for (int j = 0; j < 4; ++j) {
        const float p = __expf(sv[f][j] - mn);
        rs += p;
        const bf16 pb = (bf16)p;
        if (f == 0) pa0[j] = pb;
        else if (f == 1) pa0[4 + j] = pb;
        else if (f == 2) pa1[j] = pb;
        else pa1[4 + j] = pb;
      }
    rs += __shfl_xor(rs, 16, 64);
    rs += __shfl_xor(rs, 32, 64);
    l = l * resc + rs;

#pragma unroll
    for (int df = 0; df < 4; ++df) {
      f32x4 t4 = oacc[df];
#pragma unroll
      for (int j = 0; j < 4; ++j) t4[j] *= resc;
      const bf16* Vr = Vt + (size_t)(df * 16 + l15) * 1024 + kb + lg * 8;
      const bf16x8 va0 = *(const bf16x8*)(Vr);
      const bf16x8 va1 = *(const bf16x8*)(Vr + 32);
      t4 = MFMA_16x16x32(va0, pa0, t4);
      t4 = MFMA_16x16x32(va1, pa1, t4);
      oacc[df] = t4;
    }
  }

  const float inv = 1.0f / l;
  const size_t orow = ((size_t)b * 1024 + qbase + l15) * 768 + h * 64;
#pragma unroll
  for (int df = 0; df < 4; ++df)
#pragma unroll
    for (int r = 0; r < 4; ++r)
      outws[orow + df * 16 + lg * 4 + r] = (bf16)(oacc[df][r] * inv);
}

// ---------------------------------------------------------------------------
extern "C" void kernel_launch(void* const* d_in, const int* in_sizes, int n_in,
                              void* d_out, int out_size, void* d_ws, size_t ws_size,
                              hipStream_t stream) {
  const float* x       = (const float*)d_in[0];
  const float* size_in = (const float*)d_in[1];
  const void*  mask    = d_in[2];
  const float* w_qkv   = (const float*)d_in[3];
  const float* w_proj  = (const float*)d_in[4];
  const float* b_proj  = (const float*)d_in[5];
  float* out = (float*)d_out;   // f32 outputs per reference dtype

  if (n_in < 6 ||
      in_sizes[0] != 6291456 || in_sizes[1] != 8192 || in_sizes[2] != 8192 ||
      in_sizes[3] != 1769472 || in_sizes[4] != 589824 || in_sizes[5] != 768)
    return;

  const size_t QS = (size_t)B_ * H_ * N_ * HD_;  // 6291456 elems
  if (ws_size < 55083024) return;

  bf16* xb    = (bf16*)d_ws;       // dead after gemm<0>; reused as attnw
  bf16* qbuf  = xb + QS;
  bf16* kbuf  = qbuf + QS;
  bf16* vtbuf = kbuf + QS;
  bf16* wqb   = vtbuf + QS;        // 1769472 elems
  bf16* wpb   = wqb + 1769472;     // 589824 elems
  float* biasb = (float*)(wpb + 589824);
  int* flags = (int*)(biasb + 8192);
  bf16* attnw = xb;

  hipMemsetAsync(flags, 0, 8, stream);
  detect_mask_kernel<<<8, 256, 0, stream>>>((const unsigned*)mask, flags);
  cvt_kernel<<<6144, 256, 0, stream>>>(x, w_qkv, w_proj, size_in, mask, flags,
                                       xb, wqb, wpb, biasb);
  gemm_bt<0><<<64 * 18, 256, 0, stream>>>(xb, wqb, nullptr, qbuf, kbuf, vtbuf, nullptr);
  kmean_kernel<<<2048, 256, 0, stream>>>(kbuf, out + (size_t)B_ * N_ * C_);
  attn_mfma<<<1536, 256, 0, stream>>>(qbuf, kbuf, vtbuf, biasb, attnw);
  gemm_bt<1><<<64 * 6, 256, 0, stream>>>(attnw, wpb, b_proj, nullptr, nullptr, nullptr, out);
}

// Round 8
// 199.085 us; speedup vs baseline: 31.0562x; 1.5212x over previous
//
#include <hip/hip_runtime.h>

typedef __bf16 bf16;
typedef __bf16 bf16x4 __attribute__((ext_vector_type(4)));
typedef __bf16 bf16x8 __attribute__((ext_vector_type(8)));
typedef float f32x4 __attribute__((ext_vector_type(4)));

#define MFMA_16x16x32(a, b, c) __builtin_amdgcn_mfma_f32_16x16x32_bf16((a), (b), (c), 0, 0, 0)

#define B_ 8
#define N_ 1024
#define C_ 768
#define H_ 12
#define HD_ 64
#define KDIM 768

__device__ __forceinline__ void gload_lds16(const void* g, void* l) {
  __builtin_amdgcn_global_load_lds(
      (const __attribute__((address_space(1))) void*)g,
      (__attribute__((address_space(3))) void*)l, 16, 0, 0);
}

// ---------------------------------------------------------------------------
// mask dtype detection (robust to int8/int32/int64 storage)
// ---------------------------------------------------------------------------
__global__ __launch_bounds__(256) void detect_mask_kernel(const unsigned* __restrict__ m32,
                                                          int* __restrict__ flags) {
  const int i = blockIdx.x * 256 + threadIdx.x;
  if (i < 2048) {
    const unsigned v = m32[i];
    if (v > 1u) atomicOr(&flags[0], 1);
    if ((i & 1) && v != 0u) atomicOr(&flags[1], 1);
  }
}

// ---------------------------------------------------------------------------
// cvt: f32 -> bf16 for x, w_qkv, w_proj; bias[b*N+n] = mask ? -1e30 : log(size)
// ---------------------------------------------------------------------------
__global__ __launch_bounds__(256) void cvt_kernel(const float* __restrict__ x,
                                                  const float* __restrict__ wq,
                                                  const float* __restrict__ wp,
                                                  const float* __restrict__ size_in,
                                                  const void* __restrict__ mask_raw,
                                                  const int* __restrict__ flags,
                                                  bf16* __restrict__ xb,
                                                  bf16* __restrict__ wqb,
                                                  bf16* __restrict__ wpb,
                                                  float* __restrict__ biasb) {
  const int i = blockIdx.x * 256 + threadIdx.x;  // grid covers 6291456/4
  {
    const float4 v = ((const float4*)x)[i];
    bf16x4 o = {(bf16)v.x, (bf16)v.y, (bf16)v.z, (bf16)v.w};
    ((bf16x4*)xb)[i] = o;
  }
  if (i < 442368) {  // 2304*768/4
    const float4 v = ((const float4*)wq)[i];
    bf16x4 o = {(bf16)v.x, (bf16)v.y, (bf16)v.z, (bf16)v.w};
    ((bf16x4*)wqb)[i] = o;
  }
  if (i < 147456) {  // 768*768/4
    const float4 v = ((const float4*)wp)[i];
    bf16x4 o = {(bf16)v.x, (bf16)v.y, (bf16)v.z, (bf16)v.w};
    ((bf16x4*)wpb)[i] = o;
  }
  if (i < B_ * N_) {
    int mv;
    if (flags[0]) {
      mv = (int)((const unsigned char*)mask_raw)[i];
    } else if (flags[1]) {
      mv = ((const int*)mask_raw)[i];
    } else {  // int64
      const unsigned* m32 = (const unsigned*)mask_raw;
      mv = (int)(m32[2 * i] | m32[2 * i + 1]);
    }
    biasb[i] = mv ? -1e30f : logf(size_in[i]);
  }
}

// ---------------------------------------------------------------------------
// GEMM (NT): out[m][o] = sum_k A[m][k] * W[o][k].  M=8192, K=768.
// MODE 0: scatter epilogue into q[B,H,N,64], k[B,H,N,64], vt[B,H,64,N]
// MODE 1: f32 epilogue outf[m*768+o] = acc + bias[o]
// ---------------------------------------------------------------------------
template <int MODE>
__global__ __launch_bounds__(256) void gemm_bt(const bf16* __restrict__ A,
                                               const bf16* __restrict__ W,
                                               const float* __restrict__ bias,
                                               bf16* __restrict__ out0,
                                               bf16* __restrict__ out1,
                                               bf16* __restrict__ out2,
                                               float* __restrict__ outf) {
  __shared__ bf16 As[128 * 64];
  __shared__ bf16 Bs[128 * 64];
  const int bid = blockIdx.x;
  const int mt = bid % 64;
  const int nt = bid / 64;
  const int t = threadIdx.x;
  const int lane = t & 63, w = t >> 6;
  const int wm = w >> 1, wn = w & 1;
  const int l15 = lane & 15, lg = lane >> 4;

  f32x4 acc[4][4] = {};

  const int srow = t >> 3;
  const int skel = (t & 7) * 8;
  const bf16* Ag = A + (size_t)(mt * 128) * KDIM;
  const bf16* Bg = W + (size_t)(nt * 128) * KDIM;

  for (int kt = 0; kt < KDIM; kt += 64) {
#pragma unroll
    for (int c = 0; c < 4; ++c) {
      gload_lds16(Ag + (size_t)(c * 32 + srow) * KDIM + kt + skel,
                  (char*)As + c * 4096 + w * 1024);
      gload_lds16(Bg + (size_t)(c * 32 + srow) * KDIM + kt + skel,
                  (char*)Bs + c * 4096 + w * 1024);
    }
    __syncthreads();
#pragma unroll
    for (int ks = 0; ks < 2; ++ks) {
      bf16x8 af[4], bfr[4];
#pragma unroll
      for (int i = 0; i < 4; ++i)
        af[i] = *(const bf16x8*)(As + (wm * 64 + i * 16 + l15) * 64 + ks * 32 + lg * 8);
#pragma unroll
      for (int i = 0; i < 4; ++i)
        bfr[i] = *(const bf16x8*)(Bs + (wn * 64 + i * 16 + l15) * 64 + ks * 32 + lg * 8);
#pragma unroll
      for (int i = 0; i < 4; ++i)
#pragma unroll
        for (int j = 0; j < 4; ++j)
          acc[i][j] = MFMA_16x16x32(af[i], bfr[j], acc[i][j]);
    }
    __syncthreads();
  }

  if (MODE == 0) {
    const int which = (nt * 128) / 768;  // 768 = 6*128, tiles never straddle
#pragma unroll
    for (int i = 0; i < 4; ++i)
#pragma unroll
      for (int j = 0; j < 4; ++j)
#pragma unroll
        for (int r = 0; r < 4; ++r) {
          const int m = mt * 128 + wm * 64 + i * 16 + lg * 4 + r;
          const int o = nt * 128 + wn * 64 + j * 16 + l15;
          const int b = m >> 10, n = m & 1023;
          const int f = o - which * 768;
          const int h = f >> 6, hd = f & 63;
          const bf16 bv = (bf16)acc[i][j][r];
          if (which == 0)
            out0[(((size_t)(b * 12 + h)) * 1024 + n) * 64 + hd] = bv;
          else if (which == 1)
            out1[(((size_t)(b * 12 + h)) * 1024 + n) * 64 + hd] = bv;
          else
            out2[(((size_t)(b * 12 + h)) * 64 + hd) * 1024 + n] = bv;
        }
  } else {
#pragma unroll
    for (int i = 0; i < 4; ++i)
#pragma unroll
      for (int j = 0; j < 4; ++j) {
        const int o = nt * 128 + wn * 64 + j * 16 + l15;
        const float bv = bias[o];
#pragma unroll
        for (int r = 0; r < 4; ++r) {
          const int m = mt * 128 + wm * 64 + i * 16 + lg * 4 + r;
          outf[(size_t)m * 768 + o] = acc[i][j][r] + bv;
        }
      }
  }
}

// ---------------------------------------------------------------------------
// k_mean (f32 out): kmean[b,n,hd] = mean_h k[b,h,n,hd]
// ---------------------------------------------------------------------------
__global__ __launch_bounds__(256) void kmean_kernel(const bf16* __restrict__ kbuf,
                                                    float* __restrict__ kmean) {
  const int i = blockIdx.x * 256 + threadIdx.x;
  if (i >= B_ * N_ * HD_) return;
  const int hd = i & 63;
  const int n = (i >> 6) & 1023;
  const int b = i >> 16;
  float s = 0.f;
#pragma unroll
  for (int h = 0; h < 12; ++h)
    s += (float)kbuf[(((size_t)(b * 12 + h)) * 1024 + n) * 64 + hd];
  kmean[i] = s * (1.0f / 12.0f);
}

// ---------------------------------------------------------------------------
// MFMA flash attention, swapped-operand form + LDS double-buffered K/V tiles.
// Block = 4 waves (each 16 q-rows), KBLK = 64, all 4 waves share one (b,h).
// K-tile staged in pi-permuted row order (pi matches the swapped-QK frag
// permutation), V-tile in natural order; both bank-swizzled slot^=(row&7)
// via PRE-SWIZZLED GLOBAL SOURCE (global_load_lds dest must be linear).
// Softmax lane-local + 2 shuffles; P never leaves the lane.
// ---------------------------------------------------------------------------
__global__ __launch_bounds__(256, 5) void attn_mfma(const bf16* __restrict__ qbuf,
                                                    const bf16* __restrict__ kbuf,
                                                    const bf16* __restrict__ vtbuf,
                                                    const float* __restrict__ biasb,
                                                    bf16* __restrict__ outws) {
  __shared__ bf16 Ks[2][4096];  // [64 rows][8 slots of 8 elems], swizzled
  __shared__ bf16 Vs[2][4096];
  const int qt = blockIdx.x & 15;
  const int bh = blockIdx.x >> 4;
  const int b = bh / 12, h = bh % 12;
  const int t = threadIdx.x, lane = t & 63, w = t >> 6;
  const int l15 = lane & 15, lg = lane >> 4;
  const int qbase = qt * 64 + w * 16;

  const bf16* Q = qbuf + ((size_t)bh * 1024 + qbase) * 64;
  const bf16* Kp = kbuf + (size_t)bh * 65536;
  const bf16* Vt = vtbuf + (size_t)bh * 65536;
  const float* bias = biasb + b * 1024;

  // Q as B-operand: col=l15 (q-row), k-slots lg*8+e = d
  const bf16x8 qb0 = *(const bf16x8*)(Q + l15 * 64 + lg * 8);
  const bf16x8 qb1 = *(const bf16x8*)(Q + l15 * 64 + 32 + lg * 8);

  // staging geometry: thread covers LDS 16B slot (row=t>>3 [+32], sl=t&7);
  // phys slot sl holds logical slot sl^(row&7); K row j holds key pi(j).
  const int srow = t >> 3;                 // 0..31
  const int dsl = (t & 7) ^ (srow & 7);    // logical slot fetched
  const int pi0 = 4 * ((srow >> 4) & 1) + 8 * ((srow >> 2) & 3) + (srow & 3);
  const bf16* srcK0 = Kp + pi0 * 64 + dsl * 8;          // rows j = srow
  const bf16* srcK1 = Kp + (32 + pi0) * 64 + dsl * 8;   // rows j = 32+srow
  const bf16* srcV0 = Vt + (size_t)srow * 1024 + dsl * 8;
  const bf16* srcV1 = Vt + (size_t)(32 + srow) * 1024 + dsl * 8;
  char* const ldsK0 = (char*)&Ks[0][0] + w * 1024;
  char* const ldsK1 = (char*)&Ks[1][0] + w * 1024;
  char* const ldsV0 = (char*)&Vs[0][0] + w * 1024;
  char* const ldsV1 = (char*)&Vs[1][0] + w * 1024;

  // prologue: stage tile 0 into buf 0
  gload_lds16(srcK0, ldsK0);
  gload_lds16(srcK1, ldsK0 + 4096 * 0 + 1024 * 4);  // rows 32..63 at +4KB
  gload_lds16(srcV0, ldsV0);
  gload_lds16(srcV1, ldsV0 + 4096);
  __syncthreads();

  const int bb0 = 8 * lg;        // bias quad base (D-row=lg*4+j)
  const int swz = l15 & 7;

  f32x4 oacc[4] = {};
  float m = -1e30f, l = 0.f;

  for (int kt = 0; kt < 16; ++kt) {
    const int cur = kt & 1;
    const int kb = kt * 64;
    if (kt < 15) {  // stage next tile into the other buffer
      const size_t ko = (size_t)(kb + 64) * 64;
      char* const nK = cur ? ldsK0 : ldsK1;
      char* const nV = cur ? ldsV0 : ldsV1;
      gload_lds16(srcK0 + ko, nK);
      gload_lds16(srcK1 + ko, nK + 4096);
      gload_lds16(srcV0 + (kb + 64), nV);
      gload_lds16(srcV1 + (kb + 64), nV + 4096);
    }

    const bf16* LK = Ks[cur];
    const bf16* LV = Vs[cur];
    float sv[4][4];
#pragma unroll
    for (int f = 0; f < 4; ++f) {
      const int cf = 32 * (f >> 1) + 4 * (f & 1);
      const bf16* kj = LK + (f * 16 + l15) * 64;
      const bf16x8 ka0 = *(const bf16x8*)(kj + (lg ^ swz) * 8);
      const bf16x8 ka1 = *(const bf16x8*)(kj + ((lg + 4) ^ swz) * 8);
      f32x4 z = {};
      z = MFMA_16x16x32(ka0, qb0, z);
      z = MFMA_16x16x32(ka1, qb1, z);
      const float4 bi = *(const float4*)(bias + kb + cf + bb0);
      sv[f][0] = z[0] * 0.125f + bi.x;
      sv[f][1] = z[1] * 0.125f + bi.y;
      sv[f][2] = z[2] * 0.125f + bi.z;
      sv[f][3] = z[3] * 0.125f + bi.w;
    }
    // max over 64 keys for this lane's q=l15: 15 local + 2 shuffles
    float mx = sv[0][0];
#pragma unroll
    for (int f = 0; f < 4; ++f)
#pragma unroll
      for (int j = 0; j < 4; ++j) mx = fmaxf(mx, sv[f][j]);
    mx = fmaxf(mx, __shfl_xor(mx, 16, 64));
    mx = fmaxf(mx, __shfl_xor(mx, 32, 64));
    const float mn = fmaxf(m, mx);
    const float resc = __expf(m - mn);
    m = mn;

    float rs = 0.f;
    bf16x8 pa0, pa1;
#pragma unroll
    for (int f = 0; f < 4; ++f)
#pragma unroll
      for (int j = 0; j < 4; ++j) {
        const float p = __expf(sv[f][j] - mn);
        rs += p;
        const bf16 pb = (bf16)p;
        if (f == 0) pa0[j] = pb;
        else if (f == 1) pa0[4 + j] = pb;
        else if (f == 2) pa1[j] = pb;
        else pa1[4 + j] = pb;
      }
    rs += __shfl_xor(rs, 16, 64);
    rs += __shfl_xor(rs, 32, 64);
    l = l * resc + rs;

#pragma unroll
    for (int df = 0; df < 4; ++df) {
      f32x4 t4 = oacc[df];
#pragma unroll
      for (int j = 0; j < 4; ++j) t4[j] *= resc;
      const bf16* vj = LV + (df * 16 + l15) * 64;
      const bf16x8 va0 = *(const bf16x8*)(vj + (lg ^ swz) * 8);
      const bf16x8 va1 = *(const bf16x8*)(vj + ((lg + 4) ^ swz) * 8);
      t4 = MFMA_16x16x32(va0, pa0, t4);
      t4 = MFMA_16x16x32(va1, pa1, t4);
      oacc[df] = t4;
    }
    __syncthreads();  // drains vmcnt (stage t+1 done) + lgkm; frees buf[cur]
  }

  const float inv = 1.0f / l;
  const size_t orow = ((size_t)b * 1024 + qbase + l15) * 768 + h * 64;
#pragma unroll
  for (int df = 0; df < 4; ++df)
#pragma unroll
    for (int r = 0; r < 4; ++r)
      outws[orow + df * 16 + lg * 4 + r] = (bf16)(oacc[df][r] * inv);
}

// ---------------------------------------------------------------------------
extern "C" void kernel_launch(void* const* d_in, const int* in_sizes, int n_in,
                              void* d_out, int out_size, void* d_ws, size_t ws_size,
                              hipStream_t stream) {
  const float* x       = (const float*)d_in[0];
  const float* size_in = (const float*)d_in[1];
  const void*  mask    = d_in[2];
  const float* w_qkv   = (const float*)d_in[3];
  const float* w_proj  = (const float*)d_in[4];
  const float* b_proj  = (const float*)d_in[5];
  float* out = (float*)d_out;   // f32 outputs per reference dtype

  if (n_in < 6 ||
      in_sizes[0] != 6291456 || in_sizes[1] != 8192 || in_sizes[2] != 8192 ||
      in_sizes[3] != 1769472 || in_sizes[4] != 589824 || in_sizes[5] != 768)
    return;

  const size_t QS = (size_t)B_ * H_ * N_ * HD_;  // 6291456 elems
  if (ws_size < 55083024) return;

  bf16* xb    = (bf16*)d_ws;       // dead after gemm<0>; reused as attnw
  bf16* qbuf  = xb + QS;
  bf16* kbuf  = qbuf + QS;
  bf16* vtbuf = kbuf + QS;
  bf16* wqb   = vtbuf + QS;        // 1769472 elems
  bf16* wpb   = wqb + 1769472;     // 589824 elems
  float* biasb = (float*)(wpb + 589824);
  int* flags = (int*)(biasb + 8192);
  bf16* attnw = xb;

  hipMemsetAsync(flags, 0, 8, stream);
  detect_mask_kernel<<<8, 256, 0, stream>>>((const unsigned*)mask, flags);
  cvt_kernel<<<6144, 256, 0, stream>>>(x, w_qkv, w_proj, size_in, mask, flags,
                                       xb, wqb, wpb, biasb);
  gemm_bt<0><<<64 * 18, 256, 0, stream>>>(xb, wqb, nullptr, qbuf, kbuf, vtbuf, nullptr);
  kmean_kernel<<<2048, 256, 0, stream>>>(kbuf, out + (size_t)B_ * N_ * C_);
  attn_mfma<<<1536, 256, 0, stream>>>(qbuf, kbuf, vtbuf, biasb, attnw);
  gemm_bt<1><<<64 * 6, 256, 0, stream>>>(attnw, wpb, b_proj, nullptr, nullptr, nullptr, out);
}